// Round 19
// baseline (281.172 us; speedup 1.0000x reference)
//
#include <hip/hip_runtime.h>
#include <math.h>

#define B_ 4
#define S_ 1024
#define E_ 1024
#define H_ 16
#define HD_ 64

#define LOG2E 1.4426950408889634f
#define C16L2 23.08312065422341f    // 16*log2e
#define C64L2 92.33248261689365f    // 64*log2e
#define C80L2 115.41560327111706f   // 80*log2e

typedef float4 f4;
typedef _Float16 f16x8 __attribute__((ext_vector_type(8)));
typedef ushort u16x8 __attribute__((ext_vector_type(8)));
typedef float f32x4 __attribute__((ext_vector_type(4)));

// async global->LDS, 16B per lane. LDS dest = wave-uniform base + lane*16.
__device__ __forceinline__ void gl16(const void* g, void* l) {
  __builtin_amdgcn_global_load_lds(
      (__attribute__((address_space(1))) void*)g,
      (__attribute__((address_space(3))) void*)l, 16, 0, 0);
}

__device__ __forceinline__ ushort f2h(float x) {
  return __builtin_bit_cast(ushort, (_Float16)x);
}
__device__ __forceinline__ float h2f(ushort h) {
  return (float)__builtin_bit_cast(_Float16, h);
}
// raw v_exp_f32 (2^x), avoiding glibc's __exp2f macro collision
__device__ __forceinline__ float exp2r(float x) {
  return __builtin_amdgcn_exp2f(x);
}
__device__ __forceinline__ f32x4 mfma16(u16x8 a, u16x8 b, f32x4 c) {
  return __builtin_amdgcn_mfma_f32_16x16x32_f16(
      __builtin_bit_cast(f16x8, a), __builtin_bit_cast(f16x8, b), c, 0, 0, 0);
}
__device__ __forceinline__ u16x8 ldg16(const ushort* p) {
  return *reinterpret_cast<const u16x8*>(p);
}
// frag load, full-row layout: row stride 64 ushorts, chunk XOR row&7 (8 slots).
__device__ __forceinline__ u16x8 ldfrag(const ushort* s, int row, int chunk) {
  return *reinterpret_cast<const u16x8*>(s + row * 64 + ((chunk ^ (row & 7)) << 3));
}

// 4-fragment register bundle (always statically indexed -> stays in VGPRs)
struct F4x { u16x8 a, b, c, d; };

// ws16 layout (units of MSZ = 1M ushorts = 2 MB):
// 0:Wqf 1:Wkf 2:Wvf 3:Wof  4..7:xf  8..11:qh  12..15:kf  16..19:vt  20..23:aoh

// ---------------------------------------------------------------------------
// prep_x: x fp32 -> fp16
// ---------------------------------------------------------------------------
__global__ __launch_bounds__(256) void prep_x(
    const float* __restrict__ x, ushort* __restrict__ xf)
{
  const size_t i = ((size_t)blockIdx.x * 256 + threadIdx.x) * 8;
  float v[8];
  *reinterpret_cast<f4*>(v)     = *reinterpret_cast<const f4*>(x + i);
  *reinterpret_cast<f4*>(v + 4) = *reinterpret_cast<const f4*>(x + i + 4);
  unsigned fw[4];
#pragma unroll
  for (int p = 0; p < 4; ++p)
    fw[p] = (unsigned)f2h(v[2 * p]) | ((unsigned)f2h(v[2 * p + 1]) << 16);
  *reinterpret_cast<uint4*>(xf + i) = make_uint4(fw[0], fw[1], fw[2], fw[3]);
}

// ---------------------------------------------------------------------------
// prep_w: W fp32 [k][n] -> transposed fp16 Wt[n][k] (all four matrices).
// ---------------------------------------------------------------------------
__global__ __launch_bounds__(256) void prep_w(
    const float* __restrict__ Wq, const float* __restrict__ Wk,
    const float* __restrict__ Wv, const float* __restrict__ Wo,
    ushort* __restrict__ ws16)
{
  const int MSZ = 1024 * 1024;
  const int mat = blockIdx.z;
  const int n0 = blockIdx.x * 64, k0 = blockIdx.y * 64;
  const float* W = mat == 0 ? Wq : mat == 1 ? Wk : mat == 2 ? Wv : Wo;
  ushort* Oh = ws16 + (size_t)mat * MSZ;

  __shared__ __align__(16) float tile[64][65];
  const int t = threadIdx.x;
  const int r = t >> 2, cq = t & 3;
#pragma unroll
  for (int j = 0; j < 4; ++j) {
    const f4 v = *reinterpret_cast<const f4*>(&W[(size_t)(k0 + r) * 1024 + n0 + cq * 16 + 4 * j]);
    tile[r][cq * 16 + 4 * j + 0] = v.x;
    tile[r][cq * 16 + 4 * j + 1] = v.y;
    tile[r][cq * 16 + 4 * j + 2] = v.z;
    tile[r][cq * 16 + 4 * j + 3] = v.w;
  }
  __syncthreads();
  unsigned hw[8];
#pragma unroll
  for (int p = 0; p < 8; ++p)
    hw[p] = (unsigned)f2h(tile[cq * 16 + 2 * p][r]) |
            ((unsigned)f2h(tile[cq * 16 + 2 * p + 1][r]) << 16);
  ushort* dh = Oh + (size_t)(n0 + r) * 1024 + k0 + cq * 16;
  *reinterpret_cast<uint4*>(dh)     = make_uint4(hw[0], hw[1], hw[2], hw[3]);
  *reinterpret_cast<uint4*>(dh + 8) = make_uint4(hw[4], hw[5], hw[6], hw[7]);
}

// ---------------------------------------------------------------------------
// MFMA GEMM (R6/R12 structure, single-buffered): C = A @ Wt^T + bias.
// Tile 64(M) x 128(N), BK=64, fp16 1-term. All staging via global_load_lds.
// OMODE 0: fp32 [m][n]; 2: fp16 [B,H,HD,S]; 3: fp16 [B,H,S,HD].
// ---------------------------------------------------------------------------
template <int OMODE>
__global__ __launch_bounds__(256) void gemm_mfma(
    const ushort* __restrict__ Ab, const ushort* __restrict__ Bhg,
    const float* __restrict__ bias, float scale,
    ushort* __restrict__ Oh, float* __restrict__ Of)
{
  const int n0 = blockIdx.x * 128;
  const int m0 = blockIdx.y * 64;
  const int t = threadIdx.x;
  const int wv = t >> 6, lane = t & 63;
  const int lr = lane & 15, lg = lane >> 4;
  const int wm = (wv >> 1) * 32, wn = (wv & 1) * 64;
  const int row8 = lane >> 3, ch8 = lane & 7;

  __shared__ __align__(16) ushort Ah_s[64 * 64];
  __shared__ __align__(16) ushort Bh_s[128 * 64];
  __shared__ __align__(16) ushort tr_s[OMODE == 2 ? 128 * 72 : 16];

  f32x4 acc[2][4];
#pragma unroll
  for (int mi = 0; mi < 2; ++mi)
#pragma unroll
    for (int ni = 0; ni < 4; ++ni) { f32x4 z = {0.f, 0.f, 0.f, 0.f}; acc[mi][ni] = z; }

  for (int kt = 0; kt < 16; ++kt) {
    const int k0 = kt * 64;
    __syncthreads();
#pragma unroll
    for (int j = 0; j < 4; ++j) {
      const int row = wv * 32 + j * 8 + row8;
      gl16(Bhg + (size_t)(n0 + row) * 1024 + k0 + ((ch8 ^ (row & 7)) << 3),
           &Bh_s[(wv * 32 + j * 8) * 64]);
    }
#pragma unroll
    for (int j = 0; j < 2; ++j) {
      const int row = wv * 16 + j * 8 + row8;
      gl16(Ab + (size_t)(m0 + row) * 1024 + k0 + ((ch8 ^ (row & 7)) << 3),
           &Ah_s[(wv * 16 + j * 8) * 64]);
    }
    __syncthreads();
#pragma unroll
    for (int ks = 0; ks < 2; ++ks) {
      const u16x8 ah0 = ldfrag(Ah_s, wm + lr, ks * 4 + lg);
      const u16x8 ah1 = ldfrag(Ah_s, wm + 16 + lr, ks * 4 + lg);
#pragma unroll
      for (int ni = 0; ni < 4; ++ni) {
        const u16x8 bh = ldfrag(Bh_s, wn + ni * 16 + lr, ks * 4 + lg);
        acc[0][ni] = mfma16(ah0, bh, acc[0][ni]);
        acc[1][ni] = mfma16(ah1, bh, acc[1][ni]);
      }
    }
  }

  // ---- epilogue ----
  if constexpr (OMODE == 2) {
    __syncthreads();
#pragma unroll
    for (int mi = 0; mi < 2; ++mi)
#pragma unroll
      for (int ni = 0; ni < 4; ++ni)
#pragma unroll
        for (int r = 0; r < 4; ++r) {
          const int n_l = wn + ni * 16 + lr, m_l = wm + mi * 16 + lg * 4 + r;
          tr_s[n_l * 72 + m_l] = f2h(acc[mi][ni][r] + bias[n0 + n_l]);
        }
    __syncthreads();
    const int row = t >> 1, hf = t & 1;
    const int n_g = n0 + row;
    const int h_ = n_g >> 6, hd = n_g & 63;
    const int b_g = m0 >> 10;
    ushort* dst = Oh + ((size_t)(b_g * 16 + h_) * 64 + hd) * 1024 + (m0 & 1023) + hf * 32;
#pragma unroll
    for (int j = 0; j < 4; ++j)
      *reinterpret_cast<uint4*>(dst + 8 * j) =
          *reinterpret_cast<const uint4*>(&tr_s[row * 72 + hf * 32 + 8 * j]);
  } else {
#pragma unroll
    for (int mi = 0; mi < 2; ++mi)
#pragma unroll
      for (int ni = 0; ni < 4; ++ni) {
        const int n = n0 + wn + ni * 16 + lr;
        const float bi = bias[n];
#pragma unroll
        for (int r = 0; r < 4; ++r) {
          const int m = m0 + wm + mi * 16 + lg * 4 + r;
          const float v = (acc[mi][ni][r] + bi) * scale;
          if constexpr (OMODE == 0) {
            Of[(size_t)m * 1024 + n] = v;
          } else {  // OMODE == 3
            const size_t addr =
                ((size_t)((m >> 10) * 16 + (n >> 6)) * 1024 + (m & 1023)) * 64 + (n & 63);
            Oh[addr] = f2h(v);
          }
        }
      }
  }
}

// ---------------------------------------------------------------------------
// MFMA dual-softmax attention: BARRIER-FREE, LDS-FREE. Each wave is fully
// independent: per-lane 16B global loads deliver exact MFMA fragments
// (swapped/permuted layouts); K/V register-double-buffered with a full
// iteration of prefetch distance (covers L2 latency); weights stored
// register->global (contiguous 32B/lane). K/V are L2-resident (384KB/bh).
// ---------------------------------------------------------------------------
__global__ __launch_bounds__(256, 4) void attn_mfma(
    const ushort* __restrict__ qh_g, const ushort* __restrict__ kf_g,
    const ushort* __restrict__ vt_g, const float* __restrict__ ge,
    float* __restrict__ attn, ushort* __restrict__ aoh)
{
  const int bid = blockIdx.x;
  const int wg = (bid & 7) * 128 + (bid >> 3);  // bijective XCD swizzle (1024 = 8*128)
  const int bh = wg >> 4, qb = wg & 15;
  const int b = bh >> 4, h = bh & 15;

  const int t = threadIdx.x;
  const int wv = t >> 6, lane = t & 63;
  const int lr = lane & 15, lg = lane >> 4;
  const int q0 = qb * 64 + wv * 16;

  // Q (fp16, pre-scaled 0.125*log2e) + G (fp32*log2e; fp16 for pass 1)
  u16x8 qh[2], gh[2];
  float gf[2][8];
#pragma unroll
  for (int ks = 0; ks < 2; ++ks) {
    const size_t qoff = ((size_t)bh * S_ + q0 + lr) * HD_ + ks * 32 + lg * 8;
    qh[ks] = ldg16(qh_g + qoff);
    const float* grow = ge + ((size_t)b * S_ + q0 + lr) * HD_ + ks * 32 + lg * 8;
    f4 g0 = *reinterpret_cast<const f4*>(grow);
    f4 g1 = *reinterpret_cast<const f4*>(grow + 4);
    gf[ks][0] = g0.x * LOG2E; gf[ks][1] = g0.y * LOG2E;
    gf[ks][2] = g0.z * LOG2E; gf[ks][3] = g0.w * LOG2E;
    gf[ks][4] = g1.x * LOG2E; gf[ks][5] = g1.y * LOG2E;
    gf[ks][6] = g1.z * LOG2E; gf[ks][7] = g1.w * LOG2E;
#pragma unroll
    for (int e = 0; e < 8; ++e) gh[ks][e] = f2h(gf[ks][e]);
  }

  const ushort* kfb = kf_g + (size_t)bh * S_ * HD_;
  const ushort* vtb = vt_g + (size_t)bh * HD_ * S_;

  float z1L = 0.f, z2L = 0.f;

  // ---------------- pass 1: z-sums, register dbuf, no barriers --------------
  // lane loads K[key rows lr, 16+lr][d = ks*32 + lg*8 ..+8] per 32-key tile.
  {
    auto p1load = [&](F4x& D, int kt) {
      const ushort* p = kfb + (size_t)kt * 2048 + lr * 64 + lg * 8;
      D.a = ldg16(p);
      D.b = ldg16(p + 32);
      D.c = ldg16(p + 1024);
      D.d = ldg16(p + 1024 + 32);
    };
    auto p1comp = [&](const F4x& D) {
      f32x4 zz = {0.f, 0.f, 0.f, 0.f};
      f32x4 s1a = mfma16(D.a, qh[0], zz); s1a = mfma16(D.b, qh[1], s1a);
      f32x4 s2a = mfma16(D.a, gh[0], zz); s2a = mfma16(D.b, gh[1], s2a);
      f32x4 s1b = mfma16(D.c, qh[0], zz); s1b = mfma16(D.d, qh[1], s1b);
      f32x4 s2b = mfma16(D.c, gh[0], zz); s2b = mfma16(D.d, gh[1], s2b);
#pragma unroll
      for (int r = 0; r < 4; ++r) {
        z1L += exp2r(s1a[r] - C16L2) + exp2r(s1b[r] - C16L2);
        z2L += exp2r(s2a[r] - C64L2) + exp2r(s2b[r] - C64L2);
      }
    };
    F4x ka, kb;
    p1load(ka, 0);
    for (int kt = 0; kt < 32; kt += 2) {
      p1load(kb, kt + 1);
      __builtin_amdgcn_sched_barrier(0);
      p1comp(ka);
      if (kt + 2 < 32) p1load(ka, kt + 2);
      __builtin_amdgcn_sched_barrier(0);
      p1comp(kb);
    }
  }

  // reduce z over the 4 lane-groups (same qrow at lanes lr+16k)
  float z1 = z1L + __shfl_xor(z1L, 16);
  z1 += __shfl_xor(z1, 32);
  float z2 = z2L + __shfl_xor(z2L, 16);
  z2 += __shfl_xor(z2, 32);
  const float rz = 1.f / (z1 * z2);

  // u = q' + g' (both log2e-scaled), single fp16 (budgeted R16)
  u16x8 uh[2];
#pragma unroll
  for (int ks = 0; ks < 2; ++ks)
#pragma unroll
    for (int e = 0; e < 8; ++e)
      uh[ks][e] = f2h(h2f(qh[ks][e]) + gf[ks][e]);

  f32x4 o[4];
#pragma unroll
  for (int dt = 0; dt < 4; ++dt) { f32x4 z = {0.f, 0.f, 0.f, 0.f}; o[dt] = z; }

  float* wrow = attn + ((size_t)bh * S_ + q0) * S_;
  const int p0 = ((lr >> 2) << 3) | (lr & 3);  // key-permuted A-row base

  // ---------------- pass 2: weights + PV, register dbuf, no barriers --------
  {
    auto p2loadk = [&](F4x& D, int kt) {
      const ushort* p = kfb + (size_t)kt * 2048 + lg * 8;
      D.a = ldg16(p + p0 * 64);
      D.b = ldg16(p + p0 * 64 + 32);
      D.c = ldg16(p + (p0 | 4) * 64);
      D.d = ldg16(p + (p0 | 4) * 64 + 32);
    };
    auto p2loadv = [&](F4x& D, int kt) {
      const ushort* p = vtb + (size_t)kt * 32 + lr * 1024 + lg * 8;
      D.a = ldg16(p);
      D.b = ldg16(p + 16 * 1024);
      D.c = ldg16(p + 32 * 1024);
      D.d = ldg16(p + 48 * 1024);
    };
    auto p2comp = [&](const F4x& K, const F4x& V, int kt) {
      f32x4 zz = {0.f, 0.f, 0.f, 0.f};
      f32x4 sA = mfma16(K.a, uh[0], zz); sA = mfma16(K.b, uh[1], sA);
      f32x4 sB = mfma16(K.c, uh[0], zz); sB = mfma16(K.d, uh[1], sB);
      float wv2[8];
      u16x8 af;
#pragma unroll
      for (int r = 0; r < 4; ++r) {
        wv2[r] = exp2r(sA[r] - C80L2) * rz;
        wv2[4 + r] = exp2r(sB[r] - C80L2) * rz;
        af[r] = f2h(wv2[r]);
        af[4 + r] = f2h(wv2[4 + r]);
      }
      o[0] = mfma16(af, V.a, o[0]);
      o[1] = mfma16(af, V.b, o[1]);
      o[2] = mfma16(af, V.c, o[2]);
      o[3] = mfma16(af, V.d, o[3]);
      float* dst = wrow + (size_t)lr * S_ + kt * 32 + lg * 8;
      *reinterpret_cast<f4*>(dst)     = make_float4(wv2[0], wv2[1], wv2[2], wv2[3]);
      *reinterpret_cast<f4*>(dst + 4) = make_float4(wv2[4], wv2[5], wv2[6], wv2[7]);
    };
    F4x ka, va, kb, vb;
    p2loadk(ka, 0);
    p2loadv(va, 0);
    for (int kt = 0; kt < 32; kt += 2) {
      p2loadk(kb, kt + 1);
      p2loadv(vb, kt + 1);
      __builtin_amdgcn_sched_barrier(0);
      p2comp(ka, va, kt);
      if (kt + 2 < 32) {
        p2loadk(ka, kt + 2);
        p2loadv(va, kt + 2);
      }
      __builtin_amdgcn_sched_barrier(0);
      p2comp(kb, vb, kt + 1);
    }
  }

  // epilogue: ao[b][s][e] fp16 (o: qrow=lg*4+r, d=dt*16+lr)
#pragma unroll
  for (int dt = 0; dt < 4; ++dt)
#pragma unroll
    for (int r = 0; r < 4; ++r)
      aoh[((size_t)b * S_ + q0 + lg * 4 + r) * E_ + h * 64 + dt * 16 + lr] =
          f2h(o[dt][r]);
}

extern "C" void kernel_launch(void* const* d_in, const int* in_sizes, int n_in,
                              void* d_out, int out_size, void* d_ws, size_t ws_size,
                              hipStream_t stream) {
  const float* x  = (const float*)d_in[0];
  const float* ge = (const float*)d_in[1];
  const float* Wq = (const float*)d_in[2];
  const float* bq = (const float*)d_in[3];
  const float* Wk = (const float*)d_in[4];
  const float* bk = (const float*)d_in[5];
  const float* Wv = (const float*)d_in[6];
  const float* bv = (const float*)d_in[7];
  const float* Wo = (const float*)d_in[8];
  const float* bo = (const float*)d_in[9];

  float* out  = (float*)d_out;
  float* attn = out + (size_t)B_ * S_ * E_;

  const size_t MSZ = 1024 * 1024;
  ushort* ws16 = (ushort*)d_ws;  // 48 MB used
  ushort* Wqf = ws16 + 0 * MSZ;
  ushort* Wkf = ws16 + 1 * MSZ;
  ushort* Wvf = ws16 + 2 * MSZ;
  ushort* Wof = ws16 + 3 * MSZ;
  ushort* xf  = ws16 + 4 * MSZ;   // fp16 x
  ushort* qh  = ws16 + 8 * MSZ;   // fp16 q (pre-scaled 0.125*log2e) [B,H,S,HD]
  ushort* kf  = ws16 + 12 * MSZ;  // fp16 k (single) [B,H,S,HD]
  ushort* vt  = ws16 + 16 * MSZ;  // fp16 v [B,H,HD,S]
  ushort* aoh = ws16 + 20 * MSZ;  // fp16 ao [B,S,E]

  dim3 blk(256);
  hipLaunchKernelGGL(prep_x, dim3(2048), blk, 0, stream, x, xf);
  hipLaunchKernelGGL(prep_w, dim3(16, 16, 4), blk, 0, stream, Wq, Wk, Wv, Wo, ws16);

  dim3 ggrid(E_ / 128, (B_ * S_) / 64);
  // Q: 1-term fp16, scale folds attention 0.125 AND log2e (exp2 softmax)
  hipLaunchKernelGGL((gemm_mfma<3>), ggrid, blk, 0, stream,
                     xf, Wqf, bq, 0.125f * LOG2E, qh, nullptr);
  // K: 1-term fp16
  hipLaunchKernelGGL((gemm_mfma<3>), ggrid, blk, 0, stream,
                     xf, Wkf, bk, 1.0f, kf, nullptr);
  // V: 1-term fp16, transposed output
  hipLaunchKernelGGL((gemm_mfma<2>), ggrid, blk, 0, stream,
                     xf, Wvf, bv, 1.0f, vt, nullptr);

  hipLaunchKernelGGL(attn_mfma, dim3(1024), blk, 0, stream,
                     qh, kf, vt, ge, attn, aoh);

  // O: 1-term fp16 -> fp32 out
  hipLaunchKernelGGL((gemm_mfma<0>), ggrid, blk, 0, stream,
                     aoh, Wof, bo, 1.0f, nullptr, out);
}

// Round 20
// 156.052 us; speedup vs baseline: 1.8018x; 1.8018x over previous
//
#include <hip/hip_runtime.h>
#include <math.h>

#define B_ 4
#define S_ 1024
#define E_ 1024
#define H_ 16
#define HD_ 64

#define LOG2E 1.4426950408889634f
#define C16L2 23.08312065422341f    // 16*log2e
#define C64L2 92.33248261689365f    // 64*log2e
#define C80L2 115.41560327111706f   // 80*log2e

typedef float4 f4;
typedef _Float16 f16x8 __attribute__((ext_vector_type(8)));
typedef ushort u16x8 __attribute__((ext_vector_type(8)));
typedef float f32x4 __attribute__((ext_vector_type(4)));

// async global->LDS, 16B per lane. LDS dest = wave-uniform base + lane*16.
__device__ __forceinline__ void gl16(const void* g, void* l) {
  __builtin_amdgcn_global_load_lds(
      (__attribute__((address_space(1))) void*)g,
      (__attribute__((address_space(3))) void*)l, 16, 0, 0);
}

__device__ __forceinline__ ushort f2h(float x) {
  return __builtin_bit_cast(ushort, (_Float16)x);
}
__device__ __forceinline__ float h2f(ushort h) {
  return (float)__builtin_bit_cast(_Float16, h);
}
// raw v_exp_f32 (2^x), avoiding glibc's __exp2f macro collision
__device__ __forceinline__ float exp2r(float x) {
  return __builtin_amdgcn_exp2f(x);
}
__device__ __forceinline__ f32x4 mfma16(u16x8 a, u16x8 b, f32x4 c) {
  return __builtin_amdgcn_mfma_f32_16x16x32_f16(
      __builtin_bit_cast(f16x8, a), __builtin_bit_cast(f16x8, b), c, 0, 0, 0);
}
// frag load, full-row layout: row stride 64 ushorts, chunk XOR row&7 (8 slots).
__device__ __forceinline__ u16x8 ldfrag(const ushort* s, int row, int chunk) {
  return *reinterpret_cast<const u16x8*>(s + row * 64 + ((chunk ^ (row & 7)) << 3));
}

// ws16 layout (units of MSZ = 1M ushorts = 2 MB):
// 0:Wqf 1:Wkf 2:Wvf 3:Wof  4..7:xf  8..11:qh  12..15:kf  16..19:vt  20..23:aoh

// ---------------------------------------------------------------------------
// prep_x: x fp32 -> fp16
// ---------------------------------------------------------------------------
__global__ __launch_bounds__(256) void prep_x(
    const float* __restrict__ x, ushort* __restrict__ xf)
{
  const size_t i = ((size_t)blockIdx.x * 256 + threadIdx.x) * 8;
  float v[8];
  *reinterpret_cast<f4*>(v)     = *reinterpret_cast<const f4*>(x + i);
  *reinterpret_cast<f4*>(v + 4) = *reinterpret_cast<const f4*>(x + i + 4);
  unsigned fw[4];
#pragma unroll
  for (int p = 0; p < 4; ++p)
    fw[p] = (unsigned)f2h(v[2 * p]) | ((unsigned)f2h(v[2 * p + 1]) << 16);
  *reinterpret_cast<uint4*>(xf + i) = make_uint4(fw[0], fw[1], fw[2], fw[3]);
}

// ---------------------------------------------------------------------------
// prep_w: W fp32 [k][n] -> transposed fp16 Wt[n][k] (all four matrices).
// ---------------------------------------------------------------------------
__global__ __launch_bounds__(256) void prep_w(
    const float* __restrict__ Wq, const float* __restrict__ Wk,
    const float* __restrict__ Wv, const float* __restrict__ Wo,
    ushort* __restrict__ ws16)
{
  const int MSZ = 1024 * 1024;
  const int mat = blockIdx.z;
  const int n0 = blockIdx.x * 64, k0 = blockIdx.y * 64;
  const float* W = mat == 0 ? Wq : mat == 1 ? Wk : mat == 2 ? Wv : Wo;
  ushort* Oh = ws16 + (size_t)mat * MSZ;

  __shared__ __align__(16) float tile[64][65];
  const int t = threadIdx.x;
  const int r = t >> 2, cq = t & 3;
#pragma unroll
  for (int j = 0; j < 4; ++j) {
    const f4 v = *reinterpret_cast<const f4*>(&W[(size_t)(k0 + r) * 1024 + n0 + cq * 16 + 4 * j]);
    tile[r][cq * 16 + 4 * j + 0] = v.x;
    tile[r][cq * 16 + 4 * j + 1] = v.y;
    tile[r][cq * 16 + 4 * j + 2] = v.z;
    tile[r][cq * 16 + 4 * j + 3] = v.w;
  }
  __syncthreads();
  unsigned hw[8];
#pragma unroll
  for (int p = 0; p < 8; ++p)
    hw[p] = (unsigned)f2h(tile[cq * 16 + 2 * p][r]) |
            ((unsigned)f2h(tile[cq * 16 + 2 * p + 1][r]) << 16);
  ushort* dh = Oh + (size_t)(n0 + r) * 1024 + k0 + cq * 16;
  *reinterpret_cast<uint4*>(dh)     = make_uint4(hw[0], hw[1], hw[2], hw[3]);
  *reinterpret_cast<uint4*>(dh + 8) = make_uint4(hw[4], hw[5], hw[6], hw[7]);
}

// ---------------------------------------------------------------------------
// MFMA GEMM core (R6/R12 structure, single-buffered). Used by gemm_qk (merged
// Q/K launch, OMODE 3) and gemm_mfma<OMODE> (V: 2, O: 0).
// ---------------------------------------------------------------------------
template <int OMODE>
__device__ __forceinline__ void gemm_body(
    const ushort* __restrict__ Ab, const ushort* __restrict__ Bhg,
    const float* __restrict__ bias, float scale,
    ushort* __restrict__ Oh, float* __restrict__ Of,
    int n0, int m0, ushort* Ah_s, ushort* Bh_s, ushort* tr_s)
{
  const int t = threadIdx.x;
  const int wv = t >> 6, lane = t & 63;
  const int lr = lane & 15, lg = lane >> 4;
  const int wm = (wv >> 1) * 32, wn = (wv & 1) * 64;
  const int row8 = lane >> 3, ch8 = lane & 7;

  f32x4 acc[2][4];
#pragma unroll
  for (int mi = 0; mi < 2; ++mi)
#pragma unroll
    for (int ni = 0; ni < 4; ++ni) { f32x4 z = {0.f, 0.f, 0.f, 0.f}; acc[mi][ni] = z; }

  for (int kt = 0; kt < 16; ++kt) {
    const int k0 = kt * 64;
    __syncthreads();
#pragma unroll
    for (int j = 0; j < 4; ++j) {
      const int row = wv * 32 + j * 8 + row8;
      gl16(Bhg + (size_t)(n0 + row) * 1024 + k0 + ((ch8 ^ (row & 7)) << 3),
           &Bh_s[(wv * 32 + j * 8) * 64]);
    }
#pragma unroll
    for (int j = 0; j < 2; ++j) {
      const int row = wv * 16 + j * 8 + row8;
      gl16(Ab + (size_t)(m0 + row) * 1024 + k0 + ((ch8 ^ (row & 7)) << 3),
           &Ah_s[(wv * 16 + j * 8) * 64]);
    }
    __syncthreads();
#pragma unroll
    for (int ks = 0; ks < 2; ++ks) {
      const u16x8 ah0 = ldfrag(Ah_s, wm + lr, ks * 4 + lg);
      const u16x8 ah1 = ldfrag(Ah_s, wm + 16 + lr, ks * 4 + lg);
#pragma unroll
      for (int ni = 0; ni < 4; ++ni) {
        const u16x8 bh = ldfrag(Bh_s, wn + ni * 16 + lr, ks * 4 + lg);
        acc[0][ni] = mfma16(ah0, bh, acc[0][ni]);
        acc[1][ni] = mfma16(ah1, bh, acc[1][ni]);
      }
    }
  }

  if constexpr (OMODE == 2) {
    __syncthreads();
#pragma unroll
    for (int mi = 0; mi < 2; ++mi)
#pragma unroll
      for (int ni = 0; ni < 4; ++ni)
#pragma unroll
        for (int r = 0; r < 4; ++r) {
          const int n_l = wn + ni * 16 + lr, m_l = wm + mi * 16 + lg * 4 + r;
          tr_s[n_l * 72 + m_l] = f2h(acc[mi][ni][r] + bias[n0 + n_l]);
        }
    __syncthreads();
    const int row = t >> 1, hf = t & 1;
    const int n_g = n0 + row;
    const int h_ = n_g >> 6, hd = n_g & 63;
    const int b_g = m0 >> 10;
    ushort* dst = Oh + ((size_t)(b_g * 16 + h_) * 64 + hd) * 1024 + (m0 & 1023) + hf * 32;
#pragma unroll
    for (int j = 0; j < 4; ++j)
      *reinterpret_cast<uint4*>(dst + 8 * j) =
          *reinterpret_cast<const uint4*>(&tr_s[row * 72 + hf * 32 + 8 * j]);
  } else {
#pragma unroll
    for (int mi = 0; mi < 2; ++mi)
#pragma unroll
      for (int ni = 0; ni < 4; ++ni) {
        const int n = n0 + wn + ni * 16 + lr;
        const float bi = bias[n];
#pragma unroll
        for (int r = 0; r < 4; ++r) {
          const int m = m0 + wm + mi * 16 + lg * 4 + r;
          const float v = (acc[mi][ni][r] + bi) * scale;
          if constexpr (OMODE == 0) {
            Of[(size_t)m * 1024 + n] = v;
          } else {  // OMODE == 3
            const size_t addr =
                ((size_t)((m >> 10) * 16 + (n >> 6)) * 1024 + (m & 1023)) * 64 + (n & 63);
            Oh[addr] = f2h(v);
          }
        }
      }
  }
}

template <int OMODE>
__global__ __launch_bounds__(256) void gemm_mfma(
    const ushort* __restrict__ Ab, const ushort* __restrict__ Bhg,
    const float* __restrict__ bias, float scale,
    ushort* __restrict__ Oh, float* __restrict__ Of)
{
  __shared__ __align__(16) ushort Ah_s[64 * 64];
  __shared__ __align__(16) ushort Bh_s[128 * 64];
  __shared__ __align__(16) ushort tr_s[OMODE == 2 ? 128 * 72 : 16];
  gemm_body<OMODE>(Ab, Bhg, bias, scale, Oh, Of,
                   blockIdx.x * 128, blockIdx.y * 64, Ah_s, Bh_s, tr_s);
}

// merged Q/K launch: blockIdx.z selects weights/bias/scale/output (OMODE 3)
__global__ __launch_bounds__(256) void gemm_qk(
    const ushort* __restrict__ Ab,
    const ushort* __restrict__ Bq, const ushort* __restrict__ Bk,
    const float* __restrict__ bq, const float* __restrict__ bk,
    float sq, float sk,
    ushort* __restrict__ Oq, ushort* __restrict__ Ok)
{
  __shared__ __align__(16) ushort Ah_s[64 * 64];
  __shared__ __align__(16) ushort Bh_s[128 * 64];
  const int z = blockIdx.z;
  gemm_body<3>(Ab, z ? Bk : Bq, z ? bk : bq, z ? sk : sq, z ? Ok : Oq, nullptr,
               blockIdx.x * 128, blockIdx.y * 64, Ah_s, Bh_s, nullptr);
}

// ---------------------------------------------------------------------------
// MFMA dual-softmax attention (R18 structure): counted-vmcnt, swapped QK^T,
// register-direct weight stores. Pass 1 uses 128-key tiles (8 iters, same
// 32KB LDS as two 16KB buffers); pass 2 KVBLK=64 (half-split layout).
// pass1: 4 loads/iter -> vmcnt(4/0); pass2: 4 loads + 4 stores -> vmcnt(4/8/4).
// ---------------------------------------------------------------------------
__global__ __launch_bounds__(256) void attn_mfma(
    const ushort* __restrict__ qh_g, const ushort* __restrict__ kf_g,
    const ushort* __restrict__ vt_g, const float* __restrict__ ge,
    float* __restrict__ attn, ushort* __restrict__ aoh)
{
  __shared__ __align__(16) ushort smem[16384];   // 32KB union
  // pass 1: buf c = smem + c*8192 (128 keys x 64 d, full-row layout)
  // pass 2: kh c = smem + c*4096; vt c = smem + 8192 + c*4096 (half-split)

  const int bid = blockIdx.x;
  const int wg = (bid & 7) * 128 + (bid >> 3);  // bijective XCD swizzle (1024 = 8*128)
  const int bh = wg >> 4, qb = wg & 15;
  const int b = bh >> 4, h = bh & 15;

  const int t = threadIdx.x;
  const int wv = t >> 6, lane = t & 63;
  const int lr = lane & 15, lg = lane >> 4;
  const int row8 = lane >> 3, ch8 = lane & 7;
  const int q0 = qb * 64 + wv * 16;

  // Q (fp16, pre-scaled 0.125*log2e) + G (fp32*log2e kept; fp16 for pass 1)
  u16x8 qh[2], gh[2];
  float gf[2][8];
#pragma unroll
  for (int ks = 0; ks < 2; ++ks) {
    const size_t qoff = ((size_t)bh * S_ + q0 + lr) * HD_ + ks * 32 + lg * 8;
    qh[ks] = *reinterpret_cast<const u16x8*>(qh_g + qoff);
    const float* grow = ge + ((size_t)b * S_ + q0 + lr) * HD_ + ks * 32 + lg * 8;
    f4 g0 = *reinterpret_cast<const f4*>(grow);
    f4 g1 = *reinterpret_cast<const f4*>(grow + 4);
    gf[ks][0] = g0.x * LOG2E; gf[ks][1] = g0.y * LOG2E;
    gf[ks][2] = g0.z * LOG2E; gf[ks][3] = g0.w * LOG2E;
    gf[ks][4] = g1.x * LOG2E; gf[ks][5] = g1.y * LOG2E;
    gf[ks][6] = g1.z * LOG2E; gf[ks][7] = g1.w * LOG2E;
#pragma unroll
    for (int e = 0; e < 8; ++e) gh[ks][e] = f2h(gf[ks][e]);
  }

  const ushort* kfb = kf_g + (size_t)bh * S_ * HD_;
  const ushort* vtb = vt_g + (size_t)bh * HD_ * S_;

  // ---- pass-1 staging: 128 keys x 64 d, 4 gl16/thread (gemm B-stage pattern)
  auto stage_K1 = [&](int kt, int c) {
#pragma unroll
    for (int j = 0; j < 4; ++j) {
      const int row = wv * 32 + j * 8 + row8;
      gl16(kfb + (size_t)kt * 8192 + row * 64 + ((ch8 ^ (row & 7)) << 3),
           &smem[c * 8192 + (wv * 32 + j * 8) * 64]);
    }
  };
  // ---- pass-2 staging (R18 half-split layout): 64 keys/d x 64, 2 gl16 each
  auto stage_K = [&](int kt, int c) {
#pragma unroll
    for (int j = 0; j < 2; ++j) {
      const int row = wv * 16 + (lane >> 2);
      const int ch = j * 4 + (lane & 3);
      gl16(kfb + (size_t)kt * 4096 + row * 64 + ((ch ^ (row & 7)) << 3),
           &smem[c * 4096 + j * 2048 + (wv * 16) * 32]);
    }
  };
  auto stage_V = [&](int kt, int c) {
#pragma unroll
    for (int j = 0; j < 2; ++j) {
      const int row = wv * 16 + (lane >> 2);
      const int ch = j * 4 + (lane & 3);
      gl16(vtb + (size_t)kt * 64 + (size_t)row * 1024 + ((ch ^ (row & 7)) << 3),
           &smem[8192 + c * 4096 + j * 2048 + (wv * 16) * 32]);
    }
  };
  auto ldfragH = [&](const ushort* s, int row, int ch) -> u16x8 {
    const int chx = ch ^ (row & 7);
    return *reinterpret_cast<const u16x8*>(
        s + (chx >> 2) * 2048 + row * 32 + (chx & 3) * 8);
  };

  float z1L = 0.f, z2L = 0.f;

  // drain Q/G loads so vmcnt bookkeeping below is exact
  asm volatile("s_waitcnt vmcnt(0)" ::: "memory");
  __builtin_amdgcn_sched_barrier(0);

  // ---------------- pass 1: z-sums (swapped; z per-lane, qrow=lr) -----------
  stage_K1(0, 0);
  for (int kt = 0; kt < 8; ++kt) {
    if (kt < 7) {
      stage_K1(kt + 1, (kt + 1) & 1);
      asm volatile("s_waitcnt vmcnt(4)" ::: "memory");
    } else {
      asm volatile("s_waitcnt vmcnt(0)" ::: "memory");
    }
    __builtin_amdgcn_sched_barrier(0);
    __builtin_amdgcn_s_barrier();
    __builtin_amdgcn_sched_barrier(0);

    const ushort* kp = smem + (kt & 1) * 8192;
    __builtin_amdgcn_s_setprio(1);
    f32x4 s1[8], s2[8];
#pragma unroll
    for (int ct = 0; ct < 8; ++ct) {
      f32x4 z = {0.f, 0.f, 0.f, 0.f};
      s1[ct] = z; s2[ct] = z;
#pragma unroll
      for (int ks = 0; ks < 2; ++ks) {
        const u16x8 kA = ldfrag(kp, ct * 16 + lr, ks * 4 + lg);
        s1[ct] = mfma16(kA, qh[ks], s1[ct]);
        s2[ct] = mfma16(kA, gh[ks], s2[ct]);
      }
    }
    __builtin_amdgcn_s_setprio(0);
#pragma unroll
    for (int ct = 0; ct < 8; ++ct)
#pragma unroll
      for (int r = 0; r < 4; ++r) {
        z1L += exp2r(s1[ct][r] - C16L2);
        z2L += exp2r(s2[ct][r] - C64L2);
      }
    __builtin_amdgcn_s_barrier();
    __builtin_amdgcn_sched_barrier(0);
  }

  // reduce z over the 4 lane-groups (same qrow at lanes lr+16k)
  float z1 = z1L + __shfl_xor(z1L, 16);
  z1 += __shfl_xor(z1, 32);
  float z2 = z2L + __shfl_xor(z2L, 16);
  z2 += __shfl_xor(z2, 32);
  const float rz = 1.f / (z1 * z2);

  // pass-2 prologue loads fly while we finish u on the VALU
  stage_K(0, 0);
  stage_V(0, 0);

  // u = q' + g' (both log2e-scaled), single fp16 (budgeted R16)
  u16x8 uh[2];
#pragma unroll
  for (int ks = 0; ks < 2; ++ks)
#pragma unroll
    for (int e = 0; e < 8; ++e)
      uh[ks][e] = f2h(h2f(qh[ks][e]) + gf[ks][e]);

  f32x4 o[4];
#pragma unroll
  for (int dt = 0; dt < 4; ++dt) { f32x4 z = {0.f, 0.f, 0.f, 0.f}; o[dt] = z; }

  float* wrow = attn + ((size_t)bh * S_ + q0) * S_;
  const int prowBase = ((lr >> 2) << 3) | (lr & 3);  // key-permuted A-row base

  // ---------------- pass 2: weights + PV, counted-vmcnt dbuf ----------------
  for (int kt = 0; kt < 16; ++kt) {
    if (kt < 15) {
      stage_K(kt + 1, (kt + 1) & 1);
      stage_V(kt + 1, (kt + 1) & 1);
      if (kt == 0) asm volatile("s_waitcnt vmcnt(4)" ::: "memory");
      else         asm volatile("s_waitcnt vmcnt(8)" ::: "memory");
    } else {
      asm volatile("s_waitcnt vmcnt(4)" ::: "memory");  // [stage15:4][stores14:4]
    }
    __builtin_amdgcn_sched_barrier(0);
    __builtin_amdgcn_s_barrier();
    __builtin_amdgcn_sched_barrier(0);

    const int c = kt & 1;
    const ushort* kfp = smem + c * 4096;
    const ushort* vtp = smem + 8192 + c * 4096;

    // two 32-key halves; swapped QK^T with permuted K rows per half
#pragma unroll
    for (int hf = 0; hf < 2; ++hf) {
      f32x4 s12[2];
      {
        f32x4 z = {0.f, 0.f, 0.f, 0.f};
        s12[0] = z; s12[1] = z;
      }
      __builtin_amdgcn_s_setprio(1);
#pragma unroll
      for (int ks = 0; ks < 2; ++ks) {
        const u16x8 kA0 = ldfragH(kfp, hf * 32 + prowBase, ks * 4 + lg);
        const u16x8 kA1 = ldfragH(kfp, hf * 32 + (prowBase | 4), ks * 4 + lg);
        s12[0] = mfma16(kA0, uh[ks], s12[0]);
        s12[1] = mfma16(kA1, uh[ks], s12[1]);
      }
      __builtin_amdgcn_s_setprio(0);

      // weights (register-resident): lane holds w[qrow=lr][key hf*32+lg*8+e]
      float wv2[8];
      u16x8 af;
#pragma unroll
      for (int ct = 0; ct < 2; ++ct)
#pragma unroll
        for (int r = 0; r < 4; ++r) {
          const float w = exp2r(s12[ct][r] - C80L2) * rz;
          wv2[ct * 4 + r] = w;
          af[ct * 4 + r] = f2h(w);
        }

      // PV for this half
      __builtin_amdgcn_s_setprio(1);
#pragma unroll
      for (int dt = 0; dt < 4; ++dt) {
        const u16x8 vf = ldfragH(vtp, dt * 16 + lr, hf * 4 + lg);
        o[dt] = mfma16(af, vf, o[dt]);
      }
      __builtin_amdgcn_s_setprio(0);

      // direct register->global stores: 8 contiguous floats per lane
      {
        float* dst = wrow + (size_t)lr * S_ + kt * 64 + hf * 32 + lg * 8;
        *reinterpret_cast<f4*>(dst)     = make_float4(wv2[0], wv2[1], wv2[2], wv2[3]);
        *reinterpret_cast<f4*>(dst + 4) = make_float4(wv2[4], wv2[5], wv2[6], wv2[7]);
      }
    }
    __builtin_amdgcn_s_barrier();
    __builtin_amdgcn_sched_barrier(0);
  }

  // epilogue: ao[b][s][e] fp16 (o: qrow=lg*4+r, d=dt*16+lr)
#pragma unroll
  for (int dt = 0; dt < 4; ++dt)
#pragma unroll
    for (int r = 0; r < 4; ++r)
      aoh[((size_t)b * S_ + q0 + lg * 4 + r) * E_ + h * 64 + dt * 16 + lr] =
          f2h(o[dt][r]);
}

extern "C" void kernel_launch(void* const* d_in, const int* in_sizes, int n_in,
                              void* d_out, int out_size, void* d_ws, size_t ws_size,
                              hipStream_t stream) {
  const float* x  = (const float*)d_in[0];
  const float* ge = (const float*)d_in[1];
  const float* Wq = (const float*)d_in[2];
  const float* bq = (const float*)d_in[3];
  const float* Wk = (const float*)d_in[4];
  const float* bk = (const float*)d_in[5];
  const float* Wv = (const float*)d_in[6];
  const float* bv = (const float*)d_in[7];
  const float* Wo = (const float*)d_in[8];
  const float* bo = (const float*)d_in[9];

  float* out  = (float*)d_out;
  float* attn = out + (size_t)B_ * S_ * E_;

  const size_t MSZ = 1024 * 1024;
  ushort* ws16 = (ushort*)d_ws;  // 48 MB used
  ushort* Wqf = ws16 + 0 * MSZ;
  ushort* Wkf = ws16 + 1 * MSZ;
  ushort* Wvf = ws16 + 2 * MSZ;
  ushort* Wof = ws16 + 3 * MSZ;
  ushort* xf  = ws16 + 4 * MSZ;   // fp16 x
  ushort* qh  = ws16 + 8 * MSZ;   // fp16 q (pre-scaled 0.125*log2e) [B,H,S,HD]
  ushort* kf  = ws16 + 12 * MSZ;  // fp16 k (single) [B,H,S,HD]
  ushort* vt  = ws16 + 16 * MSZ;  // fp16 v [B,H,HD,S]
  ushort* aoh = ws16 + 20 * MSZ;  // fp16 ao [B,S,E]

  dim3 blk(256);
  hipLaunchKernelGGL(prep_x, dim3(2048), blk, 0, stream, x, xf);
  hipLaunchKernelGGL(prep_w, dim3(16, 16, 4), blk, 0, stream, Wq, Wk, Wv, Wo, ws16);

  // Q + K merged (blockIdx.z): 1-term fp16; Q scale folds 0.125*log2e
  hipLaunchKernelGGL(gemm_qk, dim3(E_ / 128, (B_ * S_) / 64, 2), blk, 0, stream,
                     xf, Wqf, Wkf, bq, bk, 0.125f * LOG2E, 1.0f, qh, kf);
  // V: 1-term fp16, transposed output
  hipLaunchKernelGGL((gemm_mfma<2>), dim3(E_ / 128, (B_ * S_) / 64), blk, 0, stream,
                     xf, Wvf, bv, 1.0f, vt, nullptr);

  hipLaunchKernelGGL(attn_mfma, dim3(1024), blk, 0, stream,
                     qh, kf, vt, ge, attn, aoh);

  // O: 1-term fp16 -> fp32 out
  hipLaunchKernelGGL((gemm_mfma<0>), dim3(E_ / 128, (B_ * S_) / 64), blk, 0, stream,
                     aoh, Wof, bo, 1.0f, nullptr, out);
}